// Round 3
// baseline (1404.226 us; speedup 1.0000x reference)
//
#include <hip/hip_runtime.h>
#include <stdint.h>
#include <stddef.h>

// ---------------------------------------------------------------------------
// BoundingBox loss processor:
//   filter (maxconf > 0.6) -> sort by class-0 score desc (stable, idx asc)
//   -> greedy NMS (IoU > 0.5 suppress) -> per-class top-20 over kept
//   -> smooth-L1 vs targets + focal CE on (class0 top-20 > 0.5) -> /M
// ---------------------------------------------------------------------------

#define NCAP 8192
#define WROW (NCAP / 64)   // 128 u64 words per mask row
#define NCHUNK (NCAP / 64) // 128 chunks of 64 rows

typedef unsigned long long u64;

// ---------------- workspace layout (all offsets 16-byte aligned) -----------
constexpr size_t OFF_CNT   = 0;                               // 2 x u32: [0]=F, [1]=M
constexpr size_t OFF_KEYS  = 256;                             // u64[NCAP]
constexpr size_t OFF_SX1   = OFF_KEYS + 8ull * NCAP;          // f32[NCAP]
constexpr size_t OFF_SY1   = OFF_SX1 + 4ull * NCAP;
constexpr size_t OFF_SX2   = OFF_SY1 + 4ull * NCAP;
constexpr size_t OFF_SY2   = OFF_SX2 + 4ull * NCAP;
constexpr size_t OFF_AREA  = OFF_SY2 + 4ull * NCAP;
constexpr size_t OFF_SORIG = OFF_AREA + 4ull * NCAP;          // u32[NCAP]
constexpr size_t OFF_KEEPS = OFF_SORIG + 4ull * NCAP;         // u32[NCAP]
constexpr size_t OFF_KORIG = OFF_KEEPS + 4ull * NCAP;         // u32[NCAP]
constexpr size_t OFF_TOPV  = OFF_KORIG + 4ull * NCAP;         // f32[1024]
constexpr size_t OFF_TOPI  = OFF_TOPV + 4096;                 // i32[1024]
constexpr size_t OFF_DIAGT = OFF_TOPI + 4096;                 // u64[NCHUNK*64] = 64 KB
constexpr size_t OFF_MASK  = OFF_DIAGT + 8ull * NCHUNK * 64;  // u64[NCAP*WROW] = 8 MB
constexpr size_t WS_NEED_MASK = OFF_MASK + 8ull * NCAP * WROW;

// ---------------- kernels ---------------------------------------------------

__global__ void k_init(unsigned int* cnt) {
  if (threadIdx.x < 2) cnt[threadIdx.x] = 0u;
}

// Per row: valid = max over C confs > 0.6; sort key = desc(class0 score) | row.
__global__ void k_filter(const float* __restrict__ conf, int N, int C,
                         u64* __restrict__ keys,
                         unsigned int* __restrict__ cnt) {
  int row = blockIdx.x * blockDim.x + threadIdx.x;
  if (row >= NCAP) return;
  u64 key;
  if (row < N) {
    const float* cr = conf + (size_t)row * C;
    float mx = cr[0];
    for (int c = 1; c < C; ++c) mx = fmaxf(mx, cr[c]);
    unsigned int k32;
    if (mx > 0.6f) {
      union { float f; unsigned int u; } s; s.f = cr[0];
      unsigned int u = s.u;
      // monotone float->uint (ascending), then invert for descending sort
      u = (u & 0x80000000u) ? ~u : (u | 0x80000000u);
      k32 = ~u;
      if (k32 == 0xFFFFFFFFu) k32 = 0xFFFFFFFEu;  // keep 0xFFFFFFFF = invalid
      atomicAdd(&cnt[0], 1u);
    } else {
      k32 = 0xFFFFFFFFu;  // invalid rows sort last
    }
    key = ((u64)k32 << 32) | (unsigned int)row;
  } else {
    key = ((u64)0xFFFFFFFFu << 32);  // pad
  }
  keys[row] = key;
}

// One-block LDS bitonic sort, ascending u64 (desc score, asc row on ties).
__global__ __launch_bounds__(1024) void k_sort(u64* __restrict__ keys) {
  __shared__ u64 sk[NCAP];  // 64 KiB
  int tid = threadIdx.x;
  for (int t = tid; t < NCAP; t += 1024) sk[t] = keys[t];
  __syncthreads();
  for (unsigned int k = 2; k <= NCAP; k <<= 1) {
    for (unsigned int j = k >> 1; j > 0; j >>= 1) {
      for (int t = tid; t < NCAP; t += 1024) {
        unsigned int p = (unsigned int)t ^ j;
        if (p > (unsigned int)t) {
          bool up = ((t & k) == 0);
          u64 x = sk[t], y = sk[p];
          bool sw = up ? (x > y) : (x < y);
          if (sw) { sk[t] = y; sk[p] = x; }
        }
      }
      __syncthreads();
    }
  }
  for (int t = tid; t < NCAP; t += 1024) keys[t] = sk[t];
}

// Gather boxes into sorted order, precompute areas.
__global__ void k_gather(const float* __restrict__ loc,
                         const u64* __restrict__ keys,
                         float* __restrict__ sx1, float* __restrict__ sy1,
                         float* __restrict__ sx2, float* __restrict__ sy2,
                         float* __restrict__ sarea, unsigned int* __restrict__ sorig) {
  int p = blockIdx.x * blockDim.x + threadIdx.x;
  if (p >= NCAP) return;
  unsigned int row = (unsigned int)(keys[p] & 0xFFFFFFFFull);
  const float* b = loc + (size_t)row * 4;
  float x1 = b[0], y1 = b[1], x2 = b[2], y2 = b[3];
  sx1[p] = x1; sy1[p] = y1; sx2[p] = x2; sy2[p] = y2;
  sarea[p] = (x2 - x1) * (y2 - y1);   // numpy op order, no FMA hazard
  sorig[p] = row;
}

// Pairwise IoU>0.5 bitmask, torchvision style: 64x64 tiles, 1 wave per block.
__global__ __launch_bounds__(64) void k_mask(
    const float* __restrict__ sx1, const float* __restrict__ sy1,
    const float* __restrict__ sx2, const float* __restrict__ sy2,
    const float* __restrict__ sarea,
    u64* __restrict__ mask) {
  __shared__ float jx1[64], jy1[64], jx2[64], jy2[64], ja[64];
  int t = threadIdx.x;
  int jbase = blockIdx.y * 64;
  jx1[t] = sx1[jbase + t]; jy1[t] = sy1[jbase + t];
  jx2[t] = sx2[jbase + t]; jy2[t] = sy2[jbase + t];
  ja[t]  = sarea[jbase + t];
  __syncthreads();
  int i = blockIdx.x * 64 + t;
  float xi1 = sx1[i], yi1 = sy1[i], xi2 = sx2[i], yi2 = sy2[i], ai = sarea[i];
  u64 bits = 0ULL;
#pragma unroll 8
  for (int jj = 0; jj < 64; ++jj) {
    float xx1 = fmaxf(xi1, jx1[jj]);
    float yy1 = fmaxf(yi1, jy1[jj]);
    float xx2 = fminf(xi2, jx2[jj]);
    float yy2 = fminf(yi2, jy2[jj]);
    float w = fmaxf(xx2 - xx1, 0.0f);
    float h = fmaxf(yy2 - yy1, 0.0f);
    float inter = w * h;
    float den = ai + ja[jj] - inter;   // (ai + aj) - inter, numpy order
    float iou = inter / den;           // IEEE div; 0/0 -> NaN -> compare false
    if (iou > 0.5f) bits |= (1ULL << jj);
  }
  mask[(size_t)i * WROW + blockIdx.y] = bits;
}

// Transposed diagonal blocks: diagT[c*64 + j] bit r = mask row (64c+r) bit (64c+j).
// Lane j of block c ends up holding "which rows of chunk c suppress column j".
__global__ __launch_bounds__(64) void k_diagt(const u64* __restrict__ mask,
                                              u64* __restrict__ diagT) {
  __shared__ u64 rows[64];
  int c = blockIdx.x;
  int j = threadIdx.x;
  rows[j] = mask[(size_t)(c * 64 + j) * WROW + c];
  __syncthreads();
  u64 col = 0;
#pragma unroll
  for (int r = 0; r < 64; ++r) col |= ((rows[r] >> j) & 1ull) << r;  // LDS broadcast reads
  diagT[c * 64 + j] = col;
}

// ---------------------------------------------------------------------------
// Chunked greedy scan, one wave. Removed-bitset in registers (2 u64/lane).
// Per 64-row chunk:
//   (a) broadcast this chunk's 64 suppression bits from the register bitset
//   (b) resolve within-chunk greedy in registers: ctz + ballot per kept row
//       (lane j holds diagT column j = which chunk rows suppress j)
//   (c) OR the KEPT rows' full mask rows into the bitset — batched 16
//       coalesced 16B loads per round; suppressed rows are never loaded.
// ---------------------------------------------------------------------------
__global__ __launch_bounds__(64) void k_scan(
    const u64* __restrict__ mask,
    const u64* __restrict__ diagT,
    unsigned int* __restrict__ cnt,
    unsigned int* __restrict__ keeps) {
  const int lane = threadIdx.x;
  const int F = (int)cnt[0];
  const ulonglong2* __restrict__ mrow2 = (const ulonglong2*)mask;  // 64 per row
  u64 remA = 0, remB = 0;   // removed-set words 2*lane, 2*lane+1
  int K = 0;

  const int nchunks = (F + 63) >> 6;
  u64 Dcur = diagT[lane];   // chunk 0 columns

  for (int c = 0; c < nchunks; ++c) {
    // prefetch next chunk's columns (independent of everything)
    int cn = (c + 1 < NCHUNK) ? (c + 1) : c;
    u64 Dnext = diagT[cn * 64 + lane];

    // (a) suppression bits for this chunk's 64 rows
    u64 sel = (c & 1) ? remB : remA;
    u64 sup = (u64)__shfl((long long)sel, c >> 1);

    // valid rows in this chunk
    int rem_rows = F - c * 64;
    u64 validrows = (rem_rows >= 64) ? ~0ull : ((1ull << rem_rows) - 1ull);

    // (b) within-chunk greedy, all in registers
    u64 undec = validrows & ~sup;
    u64 keep = 0;
    const int cbase = c * 64;
    while (undec) {
      int r = __builtin_ctzll(undec);
      keep |= 1ull << r;
      if (lane == 0) keeps[K] = (unsigned int)(cbase + r);
      ++K;
      bool dead = (lane > r) && ((Dcur >> r) & 1ull);
      u64 deadmask = __ballot(dead);
      undec = (undec & (undec - 1)) & ~deadmask;
    }

    // (c) OR kept rows' full mask rows into the removed-set, 16 rows/batch
    u64 km = keep;
    while (km) {
#define SCAN_LD(t)                                                         \
      bool val##t = (km != 0);                                             \
      int r##t = val##t ? __builtin_ctzll(km) : 0;                         \
      km = val##t ? (km & (km - 1)) : km;                                  \
      ulonglong2 v##t = mrow2[(size_t)(cbase + r##t) * 64 + lane];
      SCAN_LD(0)  SCAN_LD(1)  SCAN_LD(2)  SCAN_LD(3)
      SCAN_LD(4)  SCAN_LD(5)  SCAN_LD(6)  SCAN_LD(7)
      SCAN_LD(8)  SCAN_LD(9)  SCAN_LD(10) SCAN_LD(11)
      SCAN_LD(12) SCAN_LD(13) SCAN_LD(14) SCAN_LD(15)
#undef SCAN_LD
#define SCAN_OR(t)                                                         \
      { u64 m##t = val##t ? ~0ull : 0ull;                                  \
        remA |= v##t.x & m##t; remB |= v##t.y & m##t; }
      SCAN_OR(0)  SCAN_OR(1)  SCAN_OR(2)  SCAN_OR(3)
      SCAN_OR(4)  SCAN_OR(5)  SCAN_OR(6)  SCAN_OR(7)
      SCAN_OR(8)  SCAN_OR(9)  SCAN_OR(10) SCAN_OR(11)
      SCAN_OR(12) SCAN_OR(13) SCAN_OR(14) SCAN_OR(15)
#undef SCAN_OR
    }

    Dcur = Dnext;
  }
  if (lane == 0) cnt[1] = (unsigned int)K;
}

// Fallback (small workspace): on-the-fly IoU greedy scan in one block.
__global__ __launch_bounds__(256) void k_scan_nomask(
    const float* __restrict__ sx1, const float* __restrict__ sy1,
    const float* __restrict__ sx2, const float* __restrict__ sy2,
    const float* __restrict__ sarea,
    unsigned int* __restrict__ cnt,
    unsigned int* __restrict__ keeps) {
  __shared__ unsigned char sup[NCAP];
  __shared__ int sK;
  int tid = threadIdx.x;
  int F = (int)cnt[0];
  for (int j = tid; j < NCAP; j += 256) sup[j] = 0;
  if (tid == 0) sK = 0;
  __syncthreads();
  for (int i = 0; i < F; ++i) {
    if (!sup[i]) {
      if (tid == 0) keeps[sK++] = (unsigned int)i;
      float xi1 = sx1[i], yi1 = sy1[i], xi2 = sx2[i], yi2 = sy2[i], ai = sarea[i];
      for (int j = i + 1 + tid; j < F; j += 256) {
        if (sup[j]) continue;
        float xx1 = fmaxf(xi1, sx1[j]);
        float yy1 = fmaxf(yi1, sy1[j]);
        float xx2 = fminf(xi2, sx2[j]);
        float yy2 = fminf(yi2, sy2[j]);
        float w = fmaxf(xx2 - xx1, 0.0f);
        float h = fmaxf(yy2 - yy1, 0.0f);
        float inter = w * h;
        float iou = inter / (ai + sarea[j] - inter);
        if (iou > 0.5f) sup[j] = 1;
      }
    }
    __syncthreads();
  }
  if (tid == 0) cnt[1] = (unsigned int)sK;
}

// kept (sorted-space) -> original row indices
__global__ void k_keptorig(const unsigned int* __restrict__ sorig,
                           const unsigned int* __restrict__ keeps,
                           unsigned int* __restrict__ korig,
                           const unsigned int* __restrict__ cnt) {
  int j = blockIdx.x * blockDim.x + threadIdx.x;
  if (j < (int)cnt[1]) korig[j] = sorig[keeps[j]];
}

// Per class (block), top-KT over the M kept boxes; lax.top_k tie semantics.
__global__ __launch_bounds__(256) void k_topk(
    const float* __restrict__ conf,
    const unsigned int* __restrict__ korig,
    const unsigned int* __restrict__ cnt,
    int C, int KT,
    float* __restrict__ topv, int* __restrict__ topi) {
  __shared__ float col[NCAP];
  __shared__ unsigned char flags[NCAP];
  __shared__ float rv[256];
  __shared__ int ri[256];
  int tid = threadIdx.x;
  int c = blockIdx.x;
  int M = (int)cnt[1];
  for (int j = tid; j < M; j += 256) {
    col[j] = conf[(size_t)korig[j] * C + c];
    flags[j] = 0;
  }
  __syncthreads();
  for (int t = 0; t < KT; ++t) {
    float bv = -3.402823466e+38f;
    int bj = 0x7FFFFFFF;
    for (int j = tid; j < M; j += 256) {
      if (flags[j]) continue;
      float v = col[j];
      if (v > bv || (v == bv && j < bj)) { bv = v; bj = j; }
    }
    rv[tid] = bv; ri[tid] = bj;
    __syncthreads();
    for (int s = 128; s > 0; s >>= 1) {
      if (tid < s) {
        float v2 = rv[tid + s]; int j2 = ri[tid + s];
        if (v2 > rv[tid] || (v2 == rv[tid] && j2 < ri[tid])) { rv[tid] = v2; ri[tid] = j2; }
      }
      __syncthreads();
    }
    if (tid == 0) {
      int w = ri[0];
      if (w == 0x7FFFFFFF) w = 0;    // M < KT safety; reference would crash here
      else flags[w] = 1;
      topv[c * KT + t] = rv[0];
      topi[c * KT + t] = w;
    }
    __syncthreads();
  }
}

// Final scalar: smooth-L1 over (KT, C, 4) gathered boxes + focal CE on
// (class0 top-KT > 0.5), divided by M.
__global__ __launch_bounds__(256) void k_loss(
    const float* __restrict__ loc, const float* __restrict__ tb,
    const int* __restrict__ labels,
    const unsigned int* __restrict__ korig,
    const float* __restrict__ topv, const int* __restrict__ topi,
    const unsigned int* __restrict__ cnt, int C, int KT,
    float* __restrict__ out) {
  __shared__ float red[256];
  int tid = threadIdx.x;
  int F = (int)cnt[0];
  int M = (int)cnt[1];
  if (F == 0 || M == 0) {
    if (tid == 0) out[0] = 0.001f;
    return;
  }
  int total = KT * C * 4;
  float part = 0.0f;
  for (int e = tid; e < total; e += 256) {
    int d = e & 3;
    int q = e >> 2;
    int c = q % C;
    int i = q / C;
    int j = topi[c * KT + i];
    unsigned int orow = korig[j];
    float pred = loc[(size_t)orow * 4 + d];
    float tg = tb[c * 4 + d];
    float dd = fabsf(pred - tg);
    part += (dd < 1.0f) ? (0.5f * dd * dd) : (dd - 0.5f);
  }
  red[tid] = part;
  __syncthreads();
  for (int s = 128; s > 0; s >>= 1) {
    if (tid < s) red[tid] += red[tid + s];
    __syncthreads();
  }
  if (tid == 0) {
    float loc_loss = red[0];
    float mx = -3.402823466e+38f;
    for (int i = 0; i < KT; ++i) {
      float x = (topv[i] > 0.5f) ? 1.0f : 0.0f;   // class 0 column
      mx = fmaxf(mx, x);
    }
    float ssum = 0.0f;
    for (int i = 0; i < KT; ++i) {
      float x = (topv[i] > 0.5f) ? 1.0f : 0.0f;
      ssum += expf(x - mx);
    }
    float lse = mx + logf(ssum);
    float ce = 0.0f;
    for (int i = 0; i < KT; ++i) {
      float x = (topv[i] > 0.5f) ? 1.0f : 0.0f;
      ce += (float)labels[i] * (x - lse);
    }
    ce = -ce;
    float pt = expf(-ce);
    float om = 1.0f - pt;
    float conf_loss = 0.25f * om * om * ce;   // ALPHA=0.25, GAMMA=2
    out[0] = (loc_loss + conf_loss) / (float)M;
  }
}

// ---------------- host ------------------------------------------------------

extern "C" void kernel_launch(void* const* d_in, const int* in_sizes, int n_in,
                              void* d_out, int out_size, void* d_ws, size_t ws_size,
                              hipStream_t stream) {
  (void)n_in; (void)out_size;
  const float* loc    = (const float*)d_in[0];
  const float* conf   = (const float*)d_in[1];
  const float* tb     = (const float*)d_in[2];
  const int*   labels = (const int*)d_in[3];
  float* out = (float*)d_out;

  int N = in_sizes[0] / 4;
  if (N > NCAP) N = NCAP;
  int C  = (N > 0) ? (in_sizes[1] / N) : 20;
  int KT = in_sizes[3];

  char* ws = (char*)d_ws;
  unsigned int* cnt   = (unsigned int*)(ws + OFF_CNT);
  u64*          keys  = (u64*)(ws + OFF_KEYS);
  float*        sx1   = (float*)(ws + OFF_SX1);
  float*        sy1   = (float*)(ws + OFF_SY1);
  float*        sx2   = (float*)(ws + OFF_SX2);
  float*        sy2   = (float*)(ws + OFF_SY2);
  float*        sarea = (float*)(ws + OFF_AREA);
  unsigned int* sorig = (unsigned int*)(ws + OFF_SORIG);
  unsigned int* keeps = (unsigned int*)(ws + OFF_KEEPS);
  unsigned int* korig = (unsigned int*)(ws + OFF_KORIG);
  float*        topv  = (float*)(ws + OFF_TOPV);
  int*          topi  = (int*)(ws + OFF_TOPI);
  u64*          diagT = (u64*)(ws + OFF_DIAGT);
  u64*          mask  = (u64*)(ws + OFF_MASK);

  bool use_mask = (ws_size >= WS_NEED_MASK);

  k_init<<<1, 64, 0, stream>>>(cnt);
  k_filter<<<NCAP / 256, 256, 0, stream>>>(conf, N, C, keys, cnt);
  k_sort<<<1, 1024, 0, stream>>>(keys);
  k_gather<<<NCAP / 256, 256, 0, stream>>>(loc, keys, sx1, sy1, sx2, sy2, sarea, sorig);
  if (use_mask) {
    k_mask<<<dim3(WROW, WROW), 64, 0, stream>>>(sx1, sy1, sx2, sy2, sarea, mask);
    k_diagt<<<NCHUNK, 64, 0, stream>>>(mask, diagT);
    k_scan<<<1, 64, 0, stream>>>(mask, diagT, cnt, keeps);
  } else {
    k_scan_nomask<<<1, 256, 0, stream>>>(sx1, sy1, sx2, sy2, sarea, cnt, keeps);
  }
  k_keptorig<<<NCAP / 256, 256, 0, stream>>>(sorig, keeps, korig, cnt);
  k_topk<<<C, 256, 0, stream>>>(conf, korig, cnt, C, KT, topv, topi);
  k_loss<<<1, 256, 0, stream>>>(loc, tb, labels, korig, topv, topi, cnt, C, KT, out);
}

// Round 4
// 1301.403 us; speedup vs baseline: 1.0790x; 1.0790x over previous
//
#include <hip/hip_runtime.h>
#include <stdint.h>
#include <stddef.h>

// ---------------------------------------------------------------------------
// BoundingBox loss processor:
//   filter (maxconf > 0.6) -> sort by class-0 score desc (stable, idx asc)
//   -> greedy NMS (IoU > 0.5 suppress) -> per-class top-20 over kept
//   -> smooth-L1 vs targets + focal CE on (class0 top-20 > 0.5) -> /M
// ---------------------------------------------------------------------------

#define NCAP 8192
#define WROW (NCAP / 64)   // 128 u64 words per mask row
#define NCHUNK (NCAP / 64) // 128 chunks of 64 rows

typedef unsigned long long u64;

// ---------------- workspace layout (all offsets 16-byte aligned) -----------
constexpr size_t OFF_CNT   = 0;                               // 2 x u32: [0]=F, [1]=M
constexpr size_t OFF_KEYS  = 256;                             // u64[NCAP]
constexpr size_t OFF_SX1   = OFF_KEYS + 8ull * NCAP;          // f32[NCAP]
constexpr size_t OFF_SY1   = OFF_SX1 + 4ull * NCAP;
constexpr size_t OFF_SX2   = OFF_SY1 + 4ull * NCAP;
constexpr size_t OFF_SY2   = OFF_SX2 + 4ull * NCAP;
constexpr size_t OFF_AREA  = OFF_SY2 + 4ull * NCAP;
constexpr size_t OFF_SORIG = OFF_AREA + 4ull * NCAP;          // u32[NCAP]
constexpr size_t OFF_KEEPS = OFF_SORIG + 4ull * NCAP;         // u32[NCAP]
constexpr size_t OFF_KORIG = OFF_KEEPS + 4ull * NCAP;         // u32[NCAP]
constexpr size_t OFF_TOPV  = OFF_KORIG + 4ull * NCAP;         // f32[1024]
constexpr size_t OFF_TOPI  = OFF_TOPV + 4096;                 // i32[1024]
constexpr size_t OFF_MASK  = OFF_TOPI + 4096;                 // u64[NCAP*WROW] = 8 MB
constexpr size_t WS_NEED_MASK = OFF_MASK + 8ull * NCAP * WROW;

// ---------------- kernels ---------------------------------------------------

__global__ void k_init(unsigned int* cnt) {
  if (threadIdx.x < 2) cnt[threadIdx.x] = 0u;
}

// Per row: valid = max over C confs > 0.6; sort key = desc(class0 score) | row.
__global__ void k_filter(const float* __restrict__ conf, int N, int C,
                         u64* __restrict__ keys,
                         unsigned int* __restrict__ cnt) {
  int row = blockIdx.x * blockDim.x + threadIdx.x;
  if (row >= NCAP) return;
  u64 key;
  if (row < N) {
    const float* cr = conf + (size_t)row * C;
    float mx = cr[0];
    for (int c = 1; c < C; ++c) mx = fmaxf(mx, cr[c]);
    unsigned int k32;
    if (mx > 0.6f) {
      union { float f; unsigned int u; } s; s.f = cr[0];
      unsigned int u = s.u;
      // monotone float->uint (ascending), then invert for descending sort
      u = (u & 0x80000000u) ? ~u : (u | 0x80000000u);
      k32 = ~u;
      if (k32 == 0xFFFFFFFFu) k32 = 0xFFFFFFFEu;  // keep 0xFFFFFFFF = invalid
      atomicAdd(&cnt[0], 1u);
    } else {
      k32 = 0xFFFFFFFFu;  // invalid rows sort last
    }
    key = ((u64)k32 << 32) | (unsigned int)row;
  } else {
    key = ((u64)0xFFFFFFFFu << 32);  // pad
  }
  keys[row] = key;
}

// One-block LDS bitonic sort, ascending u64 (desc score, asc row on ties).
__global__ __launch_bounds__(1024) void k_sort(u64* __restrict__ keys) {
  __shared__ u64 sk[NCAP];  // 64 KiB
  int tid = threadIdx.x;
  for (int t = tid; t < NCAP; t += 1024) sk[t] = keys[t];
  __syncthreads();
  for (unsigned int k = 2; k <= NCAP; k <<= 1) {
    for (unsigned int j = k >> 1; j > 0; j >>= 1) {
      for (int t = tid; t < NCAP; t += 1024) {
        unsigned int p = (unsigned int)t ^ j;
        if (p > (unsigned int)t) {
          bool up = ((t & k) == 0);
          u64 x = sk[t], y = sk[p];
          bool sw = up ? (x > y) : (x < y);
          if (sw) { sk[t] = y; sk[p] = x; }
        }
      }
      __syncthreads();
    }
  }
  for (int t = tid; t < NCAP; t += 1024) keys[t] = sk[t];
}

// Gather boxes into sorted order, precompute areas.
__global__ void k_gather(const float* __restrict__ loc,
                         const u64* __restrict__ keys,
                         float* __restrict__ sx1, float* __restrict__ sy1,
                         float* __restrict__ sx2, float* __restrict__ sy2,
                         float* __restrict__ sarea, unsigned int* __restrict__ sorig) {
  int p = blockIdx.x * blockDim.x + threadIdx.x;
  if (p >= NCAP) return;
  unsigned int row = (unsigned int)(keys[p] & 0xFFFFFFFFull);
  const float* b = loc + (size_t)row * 4;
  float x1 = b[0], y1 = b[1], x2 = b[2], y2 = b[3];
  sx1[p] = x1; sy1[p] = y1; sx2[p] = x2; sy2[p] = y2;
  sarea[p] = (x2 - x1) * (y2 - y1);   // numpy op order, no FMA hazard
  sorig[p] = row;
}

// Pairwise IoU>0.5 bitmask, torchvision style: 64x64 tiles, 1 wave per block.
// Lower-triangle blocks (by < bx) are never read by k_scan -> skipped.
__global__ __launch_bounds__(64) void k_mask(
    const float* __restrict__ sx1, const float* __restrict__ sy1,
    const float* __restrict__ sx2, const float* __restrict__ sy2,
    const float* __restrict__ sarea,
    u64* __restrict__ mask) {
  if (blockIdx.y < blockIdx.x) return;   // only words >= own chunk are consumed
  __shared__ float jx1[64], jy1[64], jx2[64], jy2[64], ja[64];
  int t = threadIdx.x;
  int jbase = blockIdx.y * 64;
  jx1[t] = sx1[jbase + t]; jy1[t] = sy1[jbase + t];
  jx2[t] = sx2[jbase + t]; jy2[t] = sy2[jbase + t];
  ja[t]  = sarea[jbase + t];
  __syncthreads();
  int i = blockIdx.x * 64 + t;
  float xi1 = sx1[i], yi1 = sy1[i], xi2 = sx2[i], yi2 = sy2[i], ai = sarea[i];
  u64 bits = 0ULL;
#pragma unroll 8
  for (int jj = 0; jj < 64; ++jj) {
    float xx1 = fmaxf(xi1, jx1[jj]);
    float yy1 = fmaxf(yi1, jy1[jj]);
    float xx2 = fminf(xi2, jx2[jj]);
    float yy2 = fminf(yi2, jy2[jj]);
    float w = fmaxf(xx2 - xx1, 0.0f);
    float h = fmaxf(yy2 - yy1, 0.0f);
    float inter = w * h;
    float den = ai + ja[jj] - inter;   // (ai + aj) - inter, numpy order
    float iou = inter / den;           // IEEE div; 0/0 -> NaN -> compare false
    if (iou > 0.5f) bits |= (1ULL << jj);
  }
  mask[(size_t)i * WROW + blockIdx.y] = bits;
}

// ---------------------------------------------------------------------------
// Chunked greedy scan, ONE block of 1024 threads (16 waves).
// Removed-bitset in LDS (128 u64). Per 64-row chunk c:
//   - all 1024 threads have chunk c's mask rows in registers (prefetched last
//     iteration; thread (r = tid>>4, s = tid&15) owns words {32i+2s, 32i+2s+1}
//     of row r); loads for chunk c+1 are issued FIRST (TLP prefetch).
//   - words < c never matter (those rows are already decided) -> loads and
//     ORs predicated on word >= c: halves mask traffic.
//   - diag word (word c of row r) ds_written by its holder -> wave 0 runs the
//     within-chunk greedy as a scalar chain: ctz + v_readlane, ~10 cyc/keep.
//   - kept rows' words atomicOr'd into the LDS removed-set by all threads.
// 2 barriers per chunk. No deep per-wave ILP for the compiler to destroy.
// ---------------------------------------------------------------------------
__global__ __launch_bounds__(1024) void k_scan(
    const u64* __restrict__ mask,
    unsigned int* __restrict__ cnt,
    unsigned int* __restrict__ keeps) {
  __shared__ u64 rem[WROW];   // removed-set, bit (64w+b) = sorted row suppressed
  __shared__ u64 ldsD[64];    // diag words of current chunk
  __shared__ u64 ldsKeep;
  const int tid = threadIdx.x;
  const int lane = tid & 63;
  const int F = (int)cnt[0];
  const int nchunks = (F + 63) >> 6;

  for (int w = tid; w < WROW; w += 1024) rem[w] = 0;

  const int r = tid >> 4;   // row within chunk, 0..63
  const int s = tid & 15;   // slot, 0..15
  const ulonglong2* __restrict__ m2 = (const ulonglong2*)mask;  // 64 pairs/row
  __syncthreads();          // rem init visible

  int K = 0;
  if (nchunks > 0) {
    // preload chunk 0 (threshold c=0: everything)
    size_t b0 = (size_t)r * 64;
    ulonglong2 cur0 = m2[b0 + s];
    ulonglong2 cur1 = m2[b0 + 16 + s];
    ulonglong2 cur2 = m2[b0 + 32 + s];
    ulonglong2 cur3 = m2[b0 + 48 + s];

    for (int c = 0; c < nchunks; ++c) {
      // ---- issue prefetch for chunk c+1 (predicated on word+1 >= cn) ----
      int cn = (c + 1 < nchunks) ? c + 1 : c;
      size_t nb = ((size_t)(cn << 6) + r) * 64;
      ulonglong2 nxt0 = {0, 0}, nxt1 = {0, 0}, nxt2 = {0, 0}, nxt3 = {0, 0};
      int w0 = 2 * s;            // word of .x for i=0; i adds 32
      if (w0 + 1 >= cn)      nxt0 = m2[nb + s];
      if (w0 + 33 >= cn)     nxt1 = m2[nb + 16 + s];
      if (w0 + 65 >= cn)     nxt2 = m2[nb + 32 + s];
      if (w0 + 97 >= cn)     nxt3 = m2[nb + 48 + s];

      // ---- publish diag word c of row r (holder: pair index c>>1) ----
      int pi = c >> 1;
      if (s == (pi & 15)) {
        int ii = pi >> 4;
        ulonglong2 v = (ii == 0) ? cur0 : (ii == 1) ? cur1 : (ii == 2) ? cur2 : cur3;
        ldsD[r] = (c & 1) ? v.y : v.x;
      }
      __syncthreads();   // ldsD visible; rem ORs from chunk c-1 visible

      // ---- wave 0: within-chunk greedy (scalar chain) ----
      if (tid < 64) {
        u64 sup = rem[c];
        u64 D = ldsD[lane];
        unsigned int Dlo = (unsigned int)D;
        unsigned int Dhi = (unsigned int)(D >> 32);
        int remrows = F - (c << 6);
        u64 valid = (remrows >= 64) ? ~0ull : ((1ull << remrows) - 1ull);
        u64 undec = valid & ~sup;
        u64 keep = 0;
        while (undec) {
          int rr = __builtin_ctzll(undec);
          keep |= 1ull << rr;
          unsigned int dlo = __builtin_amdgcn_readlane(Dlo, rr);
          unsigned int dhi = __builtin_amdgcn_readlane(Dhi, rr);
          u64 Dr = ((u64)dhi << 32) | dlo;
          // clear r itself explicitly: degenerate boxes give NaN self-IoU
          undec &= ~(Dr | (1ull << rr));
        }
        if (lane == 0) {
          ldsKeep = keep;
          u64 kk = keep;
          int kb = c << 6;
          while (kk) {
            int rr = __builtin_ctzll(kk); kk &= kk - 1;
            keeps[K] = (unsigned int)(kb + rr); ++K;
          }
        }
      }
      __syncthreads();   // ldsKeep visible

      // ---- all threads: OR kept rows' words (>= c) into removed-set ----
      u64 keep = ldsKeep;
      if ((keep >> r) & 1ull) {
        if (w0 >= c)      atomicOr(&rem[w0],      cur0.x);
        if (w0 + 1 >= c)  atomicOr(&rem[w0 + 1],  cur0.y);
        if (w0 + 32 >= c) atomicOr(&rem[w0 + 32], cur1.x);
        if (w0 + 33 >= c) atomicOr(&rem[w0 + 33], cur1.y);
        if (w0 + 64 >= c) atomicOr(&rem[w0 + 64], cur2.x);
        if (w0 + 65 >= c) atomicOr(&rem[w0 + 65], cur2.y);
        if (w0 + 96 >= c) atomicOr(&rem[w0 + 96], cur3.x);
        if (w0 + 97 >= c) atomicOr(&rem[w0 + 97], cur3.y);
      }
      // (next iteration's first barrier orders these ORs before rem[c+1] read)
      cur0 = nxt0; cur1 = nxt1; cur2 = nxt2; cur3 = nxt3;
    }
  }
  if (tid == 0) cnt[1] = (unsigned int)K;
}

// Fallback (small workspace): on-the-fly IoU greedy scan in one block.
__global__ __launch_bounds__(256) void k_scan_nomask(
    const float* __restrict__ sx1, const float* __restrict__ sy1,
    const float* __restrict__ sx2, const float* __restrict__ sy2,
    const float* __restrict__ sarea,
    unsigned int* __restrict__ cnt,
    unsigned int* __restrict__ keeps) {
  __shared__ unsigned char sup[NCAP];
  __shared__ int sK;
  int tid = threadIdx.x;
  int F = (int)cnt[0];
  for (int j = tid; j < NCAP; j += 256) sup[j] = 0;
  if (tid == 0) sK = 0;
  __syncthreads();
  for (int i = 0; i < F; ++i) {
    if (!sup[i]) {
      if (tid == 0) keeps[sK++] = (unsigned int)i;
      float xi1 = sx1[i], yi1 = sy1[i], xi2 = sx2[i], yi2 = sy2[i], ai = sarea[i];
      for (int j = i + 1 + tid; j < F; j += 256) {
        if (sup[j]) continue;
        float xx1 = fmaxf(xi1, sx1[j]);
        float yy1 = fmaxf(yi1, sy1[j]);
        float xx2 = fminf(xi2, sx2[j]);
        float yy2 = fminf(yi2, sy2[j]);
        float w = fmaxf(xx2 - xx1, 0.0f);
        float h = fmaxf(yy2 - yy1, 0.0f);
        float inter = w * h;
        float iou = inter / (ai + sarea[j] - inter);
        if (iou > 0.5f) sup[j] = 1;
      }
    }
    __syncthreads();
  }
  if (tid == 0) cnt[1] = (unsigned int)sK;
}

// kept (sorted-space) -> original row indices
__global__ void k_keptorig(const unsigned int* __restrict__ sorig,
                           const unsigned int* __restrict__ keeps,
                           unsigned int* __restrict__ korig,
                           const unsigned int* __restrict__ cnt) {
  int j = blockIdx.x * blockDim.x + threadIdx.x;
  if (j < (int)cnt[1]) korig[j] = sorig[keeps[j]];
}

// Per class (block), top-KT over the M kept boxes; lax.top_k tie semantics.
__global__ __launch_bounds__(256) void k_topk(
    const float* __restrict__ conf,
    const unsigned int* __restrict__ korig,
    const unsigned int* __restrict__ cnt,
    int C, int KT,
    float* __restrict__ topv, int* __restrict__ topi) {
  __shared__ float col[NCAP];
  __shared__ unsigned char flags[NCAP];
  __shared__ float rv[256];
  __shared__ int ri[256];
  int tid = threadIdx.x;
  int c = blockIdx.x;
  int M = (int)cnt[1];
  for (int j = tid; j < M; j += 256) {
    col[j] = conf[(size_t)korig[j] * C + c];
    flags[j] = 0;
  }
  __syncthreads();
  for (int t = 0; t < KT; ++t) {
    float bv = -3.402823466e+38f;
    int bj = 0x7FFFFFFF;
    for (int j = tid; j < M; j += 256) {
      if (flags[j]) continue;
      float v = col[j];
      if (v > bv || (v == bv && j < bj)) { bv = v; bj = j; }
    }
    rv[tid] = bv; ri[tid] = bj;
    __syncthreads();
    for (int ss = 128; ss > 0; ss >>= 1) {
      if (tid < ss) {
        float v2 = rv[tid + ss]; int j2 = ri[tid + ss];
        if (v2 > rv[tid] || (v2 == rv[tid] && j2 < ri[tid])) { rv[tid] = v2; ri[tid] = j2; }
      }
      __syncthreads();
    }
    if (tid == 0) {
      int w = ri[0];
      if (w == 0x7FFFFFFF) w = 0;    // M < KT safety; reference would crash here
      else flags[w] = 1;
      topv[c * KT + t] = rv[0];
      topi[c * KT + t] = w;
    }
    __syncthreads();
  }
}

// Final scalar: smooth-L1 over (KT, C, 4) gathered boxes + focal CE on
// (class0 top-KT > 0.5), divided by M.
__global__ __launch_bounds__(256) void k_loss(
    const float* __restrict__ loc, const float* __restrict__ tb,
    const int* __restrict__ labels,
    const unsigned int* __restrict__ korig,
    const float* __restrict__ topv, const int* __restrict__ topi,
    const unsigned int* __restrict__ cnt, int C, int KT,
    float* __restrict__ out) {
  __shared__ float red[256];
  int tid = threadIdx.x;
  int F = (int)cnt[0];
  int M = (int)cnt[1];
  if (F == 0 || M == 0) {
    if (tid == 0) out[0] = 0.001f;
    return;
  }
  int total = KT * C * 4;
  float part = 0.0f;
  for (int e = tid; e < total; e += 256) {
    int d = e & 3;
    int q = e >> 2;
    int c = q % C;
    int i = q / C;
    int j = topi[c * KT + i];
    unsigned int orow = korig[j];
    float pred = loc[(size_t)orow * 4 + d];
    float tg = tb[c * 4 + d];
    float dd = fabsf(pred - tg);
    part += (dd < 1.0f) ? (0.5f * dd * dd) : (dd - 0.5f);
  }
  red[tid] = part;
  __syncthreads();
  for (int s = 128; s > 0; s >>= 1) {
    if (tid < s) red[tid] += red[tid + s];
    __syncthreads();
  }
  if (tid == 0) {
    float loc_loss = red[0];
    float mx = -3.402823466e+38f;
    for (int i = 0; i < KT; ++i) {
      float x = (topv[i] > 0.5f) ? 1.0f : 0.0f;   // class 0 column
      mx = fmaxf(mx, x);
    }
    float ssum = 0.0f;
    for (int i = 0; i < KT; ++i) {
      float x = (topv[i] > 0.5f) ? 1.0f : 0.0f;
      ssum += expf(x - mx);
    }
    float lse = mx + logf(ssum);
    float ce = 0.0f;
    for (int i = 0; i < KT; ++i) {
      float x = (topv[i] > 0.5f) ? 1.0f : 0.0f;
      ce += (float)labels[i] * (x - lse);
    }
    ce = -ce;
    float pt = expf(-ce);
    float om = 1.0f - pt;
    float conf_loss = 0.25f * om * om * ce;   // ALPHA=0.25, GAMMA=2
    out[0] = (loc_loss + conf_loss) / (float)M;
  }
}

// ---------------- host ------------------------------------------------------

extern "C" void kernel_launch(void* const* d_in, const int* in_sizes, int n_in,
                              void* d_out, int out_size, void* d_ws, size_t ws_size,
                              hipStream_t stream) {
  (void)n_in; (void)out_size;
  const float* loc    = (const float*)d_in[0];
  const float* conf   = (const float*)d_in[1];
  const float* tb     = (const float*)d_in[2];
  const int*   labels = (const int*)d_in[3];
  float* out = (float*)d_out;

  int N = in_sizes[0] / 4;
  if (N > NCAP) N = NCAP;
  int C  = (N > 0) ? (in_sizes[1] / N) : 20;
  int KT = in_sizes[3];

  char* ws = (char*)d_ws;
  unsigned int* cnt   = (unsigned int*)(ws + OFF_CNT);
  u64*          keys  = (u64*)(ws + OFF_KEYS);
  float*        sx1   = (float*)(ws + OFF_SX1);
  float*        sy1   = (float*)(ws + OFF_SY1);
  float*        sx2   = (float*)(ws + OFF_SX2);
  float*        sy2   = (float*)(ws + OFF_SY2);
  float*        sarea = (float*)(ws + OFF_AREA);
  unsigned int* sorig = (unsigned int*)(ws + OFF_SORIG);
  unsigned int* keeps = (unsigned int*)(ws + OFF_KEEPS);
  unsigned int* korig = (unsigned int*)(ws + OFF_KORIG);
  float*        topv  = (float*)(ws + OFF_TOPV);
  int*          topi  = (int*)(ws + OFF_TOPI);
  u64*          mask  = (u64*)(ws + OFF_MASK);

  bool use_mask = (ws_size >= WS_NEED_MASK);

  k_init<<<1, 64, 0, stream>>>(cnt);
  k_filter<<<NCAP / 256, 256, 0, stream>>>(conf, N, C, keys, cnt);
  k_sort<<<1, 1024, 0, stream>>>(keys);
  k_gather<<<NCAP / 256, 256, 0, stream>>>(loc, keys, sx1, sy1, sx2, sy2, sarea, sorig);
  if (use_mask) {
    k_mask<<<dim3(WROW, WROW), 64, 0, stream>>>(sx1, sy1, sx2, sy2, sarea, mask);
    k_scan<<<1, 1024, 0, stream>>>(mask, cnt, keeps);
  } else {
    k_scan_nomask<<<1, 256, 0, stream>>>(sx1, sy1, sx2, sy2, sarea, cnt, keeps);
  }
  k_keptorig<<<NCAP / 256, 256, 0, stream>>>(sorig, keeps, korig, cnt);
  k_topk<<<C, 256, 0, stream>>>(conf, korig, cnt, C, KT, topv, topi);
  k_loss<<<1, 256, 0, stream>>>(loc, tb, labels, korig, topv, topi, cnt, C, KT, out);
}

// Round 5
// 952.448 us; speedup vs baseline: 1.4743x; 1.3664x over previous
//
#include <hip/hip_runtime.h>
#include <stdint.h>
#include <stddef.h>

// ---------------------------------------------------------------------------
// BoundingBox loss processor:
//   filter (maxconf > 0.6) -> sort by class-0 score desc (stable, idx asc)
//   -> greedy NMS (IoU > 0.5 suppress) -> per-class top-20 over kept
//   -> smooth-L1 vs targets + focal CE on (class0 top-20 > 0.5) -> /M
// ---------------------------------------------------------------------------

#define NCAP 8192
#define WROW (NCAP / 64)   // 128 u64 words per mask row
#define NCHUNK (NCAP / 64) // 128 chunks of 64 rows

typedef unsigned long long u64;

// ---------------- workspace layout (all offsets 16-byte aligned) -----------
constexpr size_t OFF_CNT   = 0;                               // 2 x u32: [0]=F, [1]=M
constexpr size_t OFF_KEYS  = 256;                             // u64[NCAP]
constexpr size_t OFF_SX1   = OFF_KEYS + 8ull * NCAP;          // f32[NCAP]
constexpr size_t OFF_SY1   = OFF_SX1 + 4ull * NCAP;
constexpr size_t OFF_SX2   = OFF_SY1 + 4ull * NCAP;
constexpr size_t OFF_SY2   = OFF_SX2 + 4ull * NCAP;
constexpr size_t OFF_AREA  = OFF_SY2 + 4ull * NCAP;
constexpr size_t OFF_SORIG = OFF_AREA + 4ull * NCAP;          // u32[NCAP]
constexpr size_t OFF_KEEPS = OFF_SORIG + 4ull * NCAP;         // u32[NCAP]
constexpr size_t OFF_KORIG = OFF_KEEPS + 4ull * NCAP;         // u32[NCAP]
constexpr size_t OFF_TOPV  = OFF_KORIG + 4ull * NCAP;         // f32[1024]
constexpr size_t OFF_TOPI  = OFF_TOPV + 4096;                 // i32[1024]
constexpr size_t OFF_MASK  = OFF_TOPI + 4096;                 // u64[NCAP*WROW] = 8 MB
constexpr size_t WS_NEED_MASK = OFF_MASK + 8ull * NCAP * WROW;

// ---------------- kernels ---------------------------------------------------

__global__ void k_init(unsigned int* cnt) {
  if (threadIdx.x < 2) cnt[threadIdx.x] = 0u;
}

// Per row: valid = max over C confs > 0.6; sort key = desc(class0 score) | row.
__global__ void k_filter(const float* __restrict__ conf, int N, int C,
                         u64* __restrict__ keys,
                         unsigned int* __restrict__ cnt) {
  int row = blockIdx.x * blockDim.x + threadIdx.x;
  if (row >= NCAP) return;
  u64 key;
  if (row < N) {
    const float* cr = conf + (size_t)row * C;
    float mx = cr[0];
    for (int c = 1; c < C; ++c) mx = fmaxf(mx, cr[c]);
    unsigned int k32;
    if (mx > 0.6f) {
      union { float f; unsigned int u; } s; s.f = cr[0];
      unsigned int u = s.u;
      // monotone float->uint (ascending), then invert for descending sort
      u = (u & 0x80000000u) ? ~u : (u | 0x80000000u);
      k32 = ~u;
      if (k32 == 0xFFFFFFFFu) k32 = 0xFFFFFFFEu;  // keep 0xFFFFFFFF = invalid
      atomicAdd(&cnt[0], 1u);
    } else {
      k32 = 0xFFFFFFFFu;  // invalid rows sort last
    }
    key = ((u64)k32 << 32) | (unsigned int)row;
  } else {
    key = ((u64)0xFFFFFFFFu << 32);  // pad
  }
  keys[row] = key;
}

// One-block LDS bitonic sort, ascending u64 (desc score, asc row on ties).
__global__ __launch_bounds__(1024) void k_sort(u64* __restrict__ keys) {
  __shared__ u64 sk[NCAP];  // 64 KiB
  int tid = threadIdx.x;
  for (int t = tid; t < NCAP; t += 1024) sk[t] = keys[t];
  __syncthreads();
  for (unsigned int k = 2; k <= NCAP; k <<= 1) {
    for (unsigned int j = k >> 1; j > 0; j >>= 1) {
      for (int t = tid; t < NCAP; t += 1024) {
        unsigned int p = (unsigned int)t ^ j;
        if (p > (unsigned int)t) {
          bool up = ((t & k) == 0);
          u64 x = sk[t], y = sk[p];
          bool sw = up ? (x > y) : (x < y);
          if (sw) { sk[t] = y; sk[p] = x; }
        }
      }
      __syncthreads();
    }
  }
  for (int t = tid; t < NCAP; t += 1024) keys[t] = sk[t];
}

// Gather boxes into sorted order, precompute areas.
__global__ void k_gather(const float* __restrict__ loc,
                         const u64* __restrict__ keys,
                         float* __restrict__ sx1, float* __restrict__ sy1,
                         float* __restrict__ sx2, float* __restrict__ sy2,
                         float* __restrict__ sarea, unsigned int* __restrict__ sorig) {
  int p = blockIdx.x * blockDim.x + threadIdx.x;
  if (p >= NCAP) return;
  unsigned int row = (unsigned int)(keys[p] & 0xFFFFFFFFull);
  const float* b = loc + (size_t)row * 4;
  float x1 = b[0], y1 = b[1], x2 = b[2], y2 = b[3];
  sx1[p] = x1; sy1[p] = y1; sx2[p] = x2; sy2[p] = y2;
  sarea[p] = (x2 - x1) * (y2 - y1);   // numpy op order, no FMA hazard
  sorig[p] = row;
}

// Pairwise IoU>0.5 bitmask, torchvision style: 64x64 tiles, 1 wave per block.
// Lower-triangle blocks (by < bx) are never read by k_scan -> skipped.
__global__ __launch_bounds__(64) void k_mask(
    const float* __restrict__ sx1, const float* __restrict__ sy1,
    const float* __restrict__ sx2, const float* __restrict__ sy2,
    const float* __restrict__ sarea,
    u64* __restrict__ mask) {
  if (blockIdx.y < blockIdx.x) return;   // only words >= own chunk are consumed
  __shared__ float jx1[64], jy1[64], jx2[64], jy2[64], ja[64];
  int t = threadIdx.x;
  int jbase = blockIdx.y * 64;
  jx1[t] = sx1[jbase + t]; jy1[t] = sy1[jbase + t];
  jx2[t] = sx2[jbase + t]; jy2[t] = sy2[jbase + t];
  ja[t]  = sarea[jbase + t];
  __syncthreads();
  int i = blockIdx.x * 64 + t;
  float xi1 = sx1[i], yi1 = sy1[i], xi2 = sx2[i], yi2 = sy2[i], ai = sarea[i];
  u64 bits = 0ULL;
#pragma unroll 8
  for (int jj = 0; jj < 64; ++jj) {
    float xx1 = fmaxf(xi1, jx1[jj]);
    float yy1 = fmaxf(yi1, jy1[jj]);
    float xx2 = fminf(xi2, jx2[jj]);
    float yy2 = fminf(yi2, jy2[jj]);
    float w = fmaxf(xx2 - xx1, 0.0f);
    float h = fmaxf(yy2 - yy1, 0.0f);
    float inter = w * h;
    float den = ai + ja[jj] - inter;   // (ai + aj) - inter, numpy order
    float iou = inter / den;           // IEEE div; 0/0 -> NaN -> compare false
    if (iou > 0.5f) bits |= (1ULL << jj);
  }
  mask[(size_t)i * WROW + blockIdx.y] = bits;
}

// ---------------------------------------------------------------------------
// Chunked greedy scan, ONE block of 1024 threads (16 waves).
// Per 64-row chunk h (rows [64h, 64h+64), relevant mask words >= h):
//   phase 1: thread tid loads its 4 linear 16B units of the chunk
//            (m2[h*4096 + tid + 1024k]) into REGISTERS; holders of diagonal
//            word h publish 64 u64 to ldsD.   [no LDS/VGPR staging arrays:
//            round-2/3/4 all died to the compiler spilling big register or
//            LDS pipelines — cross-barrier payload here is just 64 B/thread]
//   phase 2: wave 0 resolves the within-chunk greedy (uniform ctz+readlane).
//   phase 3: threads OR their registers into LDS rem[] for KEPT rows only
//            (ds_atomic_or_b64, word-predicated), then registers die.
// 2 barriers/chunk; rem[] (LDS, 1 KB) is the only persistent state.
// ---------------------------------------------------------------------------
__global__ __launch_bounds__(1024) void k_scan(
    const u64* __restrict__ mask,
    unsigned int* __restrict__ cnt,
    unsigned int* __restrict__ keeps) {
  __shared__ u64 rem[WROW];   // removed-set, bit (64w+b) = sorted row 64w+b dead
  __shared__ u64 ldsD[64];    // diag word h of each chunk row
  __shared__ u64 ldsKeep;
  const int tid = threadIdx.x;
  const int F = (int)cnt[0];
  const int nch = (F + 63) >> 6;
  const ulonglong2* __restrict__ m2 = (const ulonglong2*)mask;  // 64 pairs/row

  for (int w = tid; w < WROW; w += 1024) rem[w] = 0;

  const int p0 = tid & 63;    // pair index (words 2p0, 2p0+1) of each held row
  const int g0 = tid >> 6;    // row group: holds rows g0, g0+16, g0+32, g0+48
  int K = 0;

  for (int h = 0; h < nch; ++h) {
    const size_t gb = (size_t)h * 4096;   // chunk = 4096 linear 16B units
    const bool ld = (2 * p0 + 1) >= h;    // pair relevant iff top word >= h
    ulonglong2 v0 = {0,0}, v1 = {0,0}, v2 = {0,0}, v3 = {0,0};
    if (ld) {
      v0 = m2[gb + tid];
      v1 = m2[gb + tid + 1024];
      v2 = m2[gb + tid + 2048];
      v3 = m2[gb + tid + 3072];
    }
    if (p0 == (h >> 1)) {   // ld is provably true here
      ldsD[g0]      = (h & 1) ? v0.y : v0.x;
      ldsD[g0 + 16] = (h & 1) ? v1.y : v1.x;
      ldsD[g0 + 32] = (h & 1) ? v2.y : v2.x;
      ldsD[g0 + 48] = (h & 1) ? v3.y : v3.x;
    }
    __syncthreads();   // ldsD + prev chunk's rem ORs visible

    if (tid < 64) {
      u64 sup = rem[h];                    // same addr all lanes -> broadcast
      u64 D = ldsD[tid];
      unsigned int Dlo = (unsigned int)D, Dhi = (unsigned int)(D >> 32);
      int remrows = F - (h << 6);
      u64 valid = (remrows >= 64) ? ~0ull : ((1ull << remrows) - 1ull);
      u64 undec = valid & ~sup;            // uniform across wave 0
      u64 keep = 0;
      while (undec) {
        int rr = __builtin_ctzll(undec);   // uniform -> SGPR lane index
        keep |= 1ull << rr;
        unsigned int dlo = __builtin_amdgcn_readlane(Dlo, rr);
        unsigned int dhi = __builtin_amdgcn_readlane(Dhi, rr);
        // clear rr itself too: degenerate boxes can give NaN self-IoU
        undec &= ~(((u64)dhi << 32) | (u64)dlo | (1ull << rr));
      }
      if (tid == 0) {
        ldsKeep = keep;
        u64 kk = keep; int kb = h << 6;
        while (kk) { int rr = __builtin_ctzll(kk); kk &= kk - 1;
                     keeps[K] = (unsigned int)(kb + rr); ++K; }
      }
    }
    __syncthreads();   // ldsKeep visible

    const u64 keep = ldsKeep;
    if (ld && keep) {
      const int w0 = 2 * p0;
      const bool e0 = (w0 >= h);           // low word relevant?
      if ((keep >> g0) & 1ull)        { if (e0) atomicOr(&rem[w0], v0.x); atomicOr(&rem[w0+1], v0.y); }
      if ((keep >> (g0+16)) & 1ull)   { if (e0) atomicOr(&rem[w0], v1.x); atomicOr(&rem[w0+1], v1.y); }
      if ((keep >> (g0+32)) & 1ull)   { if (e0) atomicOr(&rem[w0], v2.x); atomicOr(&rem[w0+1], v2.y); }
      if ((keep >> (g0+48)) & 1ull)   { if (e0) atomicOr(&rem[w0], v3.x); atomicOr(&rem[w0+1], v3.y); }
    }
    // next iteration's first barrier orders these ORs before rem[h+1] read
  }
  if (tid == 0) cnt[1] = (unsigned int)K;
}

// Fallback (small workspace): on-the-fly IoU greedy scan in one block.
__global__ __launch_bounds__(256) void k_scan_nomask(
    const float* __restrict__ sx1, const float* __restrict__ sy1,
    const float* __restrict__ sx2, const float* __restrict__ sy2,
    const float* __restrict__ sarea,
    unsigned int* __restrict__ cnt,
    unsigned int* __restrict__ keeps) {
  __shared__ unsigned char sup[NCAP];
  __shared__ int sK;
  int tid = threadIdx.x;
  int F = (int)cnt[0];
  for (int j = tid; j < NCAP; j += 256) sup[j] = 0;
  if (tid == 0) sK = 0;
  __syncthreads();
  for (int i = 0; i < F; ++i) {
    if (!sup[i]) {
      if (tid == 0) keeps[sK++] = (unsigned int)i;
      float xi1 = sx1[i], yi1 = sy1[i], xi2 = sx2[i], yi2 = sy2[i], ai = sarea[i];
      for (int j = i + 1 + tid; j < F; j += 256) {
        if (sup[j]) continue;
        float xx1 = fmaxf(xi1, sx1[j]);
        float yy1 = fmaxf(yi1, sy1[j]);
        float xx2 = fminf(xi2, sx2[j]);
        float yy2 = fminf(yi2, sy2[j]);
        float w = fmaxf(xx2 - xx1, 0.0f);
        float h = fmaxf(yy2 - yy1, 0.0f);
        float inter = w * h;
        float iou = inter / (ai + sarea[j] - inter);
        if (iou > 0.5f) sup[j] = 1;
      }
    }
    __syncthreads();
  }
  if (tid == 0) cnt[1] = (unsigned int)sK;
}

// kept (sorted-space) -> original row indices
__global__ void k_keptorig(const unsigned int* __restrict__ sorig,
                           const unsigned int* __restrict__ keeps,
                           unsigned int* __restrict__ korig,
                           const unsigned int* __restrict__ cnt) {
  int j = blockIdx.x * blockDim.x + threadIdx.x;
  if (j < (int)cnt[1]) korig[j] = sorig[keeps[j]];
}

// Per class (block), top-KT over the M kept boxes; lax.top_k tie semantics.
__global__ __launch_bounds__(256) void k_topk(
    const float* __restrict__ conf,
    const unsigned int* __restrict__ korig,
    const unsigned int* __restrict__ cnt,
    int C, int KT,
    float* __restrict__ topv, int* __restrict__ topi) {
  __shared__ float col[NCAP];
  __shared__ unsigned char flags[NCAP];
  __shared__ float rv[256];
  __shared__ int ri[256];
  int tid = threadIdx.x;
  int c = blockIdx.x;
  int M = (int)cnt[1];
  for (int j = tid; j < M; j += 256) {
    col[j] = conf[(size_t)korig[j] * C + c];
    flags[j] = 0;
  }
  __syncthreads();
  for (int t = 0; t < KT; ++t) {
    float bv = -3.402823466e+38f;
    int bj = 0x7FFFFFFF;
    for (int j = tid; j < M; j += 256) {
      if (flags[j]) continue;
      float v = col[j];
      if (v > bv || (v == bv && j < bj)) { bv = v; bj = j; }
    }
    rv[tid] = bv; ri[tid] = bj;
    __syncthreads();
    for (int ss = 128; ss > 0; ss >>= 1) {
      if (tid < ss) {
        float v2 = rv[tid + ss]; int j2 = ri[tid + ss];
        if (v2 > rv[tid] || (v2 == rv[tid] && j2 < ri[tid])) { rv[tid] = v2; ri[tid] = j2; }
      }
      __syncthreads();
    }
    if (tid == 0) {
      int w = ri[0];
      if (w == 0x7FFFFFFF) w = 0;    // M < KT safety; reference would crash here
      else flags[w] = 1;
      topv[c * KT + t] = rv[0];
      topi[c * KT + t] = w;
    }
    __syncthreads();
  }
}

// Final scalar: smooth-L1 over (KT, C, 4) gathered boxes + focal CE on
// (class0 top-KT > 0.5), divided by M.
__global__ __launch_bounds__(256) void k_loss(
    const float* __restrict__ loc, const float* __restrict__ tb,
    const int* __restrict__ labels,
    const unsigned int* __restrict__ korig,
    const float* __restrict__ topv, const int* __restrict__ topi,
    const unsigned int* __restrict__ cnt, int C, int KT,
    float* __restrict__ out) {
  __shared__ float red[256];
  int tid = threadIdx.x;
  int F = (int)cnt[0];
  int M = (int)cnt[1];
  if (F == 0 || M == 0) {
    if (tid == 0) out[0] = 0.001f;
    return;
  }
  int total = KT * C * 4;
  float part = 0.0f;
  for (int e = tid; e < total; e += 256) {
    int d = e & 3;
    int q = e >> 2;
    int c = q % C;
    int i = q / C;
    int j = topi[c * KT + i];
    unsigned int orow = korig[j];
    float pred = loc[(size_t)orow * 4 + d];
    float tg = tb[c * 4 + d];
    float dd = fabsf(pred - tg);
    part += (dd < 1.0f) ? (0.5f * dd * dd) : (dd - 0.5f);
  }
  red[tid] = part;
  __syncthreads();
  for (int s = 128; s > 0; s >>= 1) {
    if (tid < s) red[tid] += red[tid + s];
    __syncthreads();
  }
  if (tid == 0) {
    float loc_loss = red[0];
    float mx = -3.402823466e+38f;
    for (int i = 0; i < KT; ++i) {
      float x = (topv[i] > 0.5f) ? 1.0f : 0.0f;   // class 0 column
      mx = fmaxf(mx, x);
    }
    float ssum = 0.0f;
    for (int i = 0; i < KT; ++i) {
      float x = (topv[i] > 0.5f) ? 1.0f : 0.0f;
      ssum += expf(x - mx);
    }
    float lse = mx + logf(ssum);
    float ce = 0.0f;
    for (int i = 0; i < KT; ++i) {
      float x = (topv[i] > 0.5f) ? 1.0f : 0.0f;
      ce += (float)labels[i] * (x - lse);
    }
    ce = -ce;
    float pt = expf(-ce);
    float om = 1.0f - pt;
    float conf_loss = 0.25f * om * om * ce;   // ALPHA=0.25, GAMMA=2
    out[0] = (loc_loss + conf_loss) / (float)M;
  }
}

// ---------------- host ------------------------------------------------------

extern "C" void kernel_launch(void* const* d_in, const int* in_sizes, int n_in,
                              void* d_out, int out_size, void* d_ws, size_t ws_size,
                              hipStream_t stream) {
  (void)n_in; (void)out_size;
  const float* loc    = (const float*)d_in[0];
  const float* conf   = (const float*)d_in[1];
  const float* tb     = (const float*)d_in[2];
  const int*   labels = (const int*)d_in[3];
  float* out = (float*)d_out;

  int N = in_sizes[0] / 4;
  if (N > NCAP) N = NCAP;
  int C  = (N > 0) ? (in_sizes[1] / N) : 20;
  int KT = in_sizes[3];

  char* ws = (char*)d_ws;
  unsigned int* cnt   = (unsigned int*)(ws + OFF_CNT);
  u64*          keys  = (u64*)(ws + OFF_KEYS);
  float*        sx1   = (float*)(ws + OFF_SX1);
  float*        sy1   = (float*)(ws + OFF_SY1);
  float*        sx2   = (float*)(ws + OFF_SX2);
  float*        sy2   = (float*)(ws + OFF_SY2);
  float*        sarea = (float*)(ws + OFF_AREA);
  unsigned int* sorig = (unsigned int*)(ws + OFF_SORIG);
  unsigned int* keeps = (unsigned int*)(ws + OFF_KEEPS);
  unsigned int* korig = (unsigned int*)(ws + OFF_KORIG);
  float*        topv  = (float*)(ws + OFF_TOPV);
  int*          topi  = (int*)(ws + OFF_TOPI);
  u64*          mask  = (u64*)(ws + OFF_MASK);

  bool use_mask = (ws_size >= WS_NEED_MASK);

  k_init<<<1, 64, 0, stream>>>(cnt);
  k_filter<<<NCAP / 256, 256, 0, stream>>>(conf, N, C, keys, cnt);
  k_sort<<<1, 1024, 0, stream>>>(keys);
  k_gather<<<NCAP / 256, 256, 0, stream>>>(loc, keys, sx1, sy1, sx2, sy2, sarea, sorig);
  if (use_mask) {
    k_mask<<<dim3(WROW, WROW), 64, 0, stream>>>(sx1, sy1, sx2, sy2, sarea, mask);
    k_scan<<<1, 1024, 0, stream>>>(mask, cnt, keeps);
  } else {
    k_scan_nomask<<<1, 256, 0, stream>>>(sx1, sy1, sx2, sy2, sarea, cnt, keeps);
  }
  k_keptorig<<<NCAP / 256, 256, 0, stream>>>(sorig, keeps, korig, cnt);
  k_topk<<<C, 256, 0, stream>>>(conf, korig, cnt, C, KT, topv, topi);
  k_loss<<<1, 256, 0, stream>>>(loc, tb, labels, korig, topv, topi, cnt, C, KT, out);
}